// Round 1
// baseline (976.589 us; speedup 1.0000x reference)
//
#include <hip/hip_runtime.h>
#include <hip/hip_bf16.h>
#include <stdint.h>

#define B_   64
#define S_   512
#define IN_  256
#define H_   512
#define O_   256

typedef _Float16 h16;
typedef __attribute__((ext_vector_type(2))) _Float16 half2v;

static __device__ __forceinline__ float fdot2(uint32_t w, uint32_t h, float acc) {
#if __has_builtin(__builtin_amdgcn_fdot2)
  return __builtin_amdgcn_fdot2(__builtin_bit_cast(half2v, w),
                                __builtin_bit_cast(half2v, h), acc, false);
#else
  half2v a = __builtin_bit_cast(half2v, w), b = __builtin_bit_cast(half2v, h);
  return acc + (float)a[0] * (float)b[0] + (float)a[1] * (float)b[1];
#endif
}

static __device__ __forceinline__ uint32_t pack2(float a, float b) {
  h16 lo = (h16)a, hi = (h16)b;
  uint32_t u = (uint32_t)__builtin_bit_cast(unsigned short, lo);
  uint32_t v = (uint32_t)__builtin_bit_cast(unsigned short, hi);
  return u | (v << 16);
}

// ---------------- packing kernels (f32 -> f16x2 dwords) ----------------

__global__ void k_pack_x(const float2* __restrict__ x2, uint32_t* __restrict__ xpk, int n) {
  int i = blockIdx.x * blockDim.x + threadIdx.x;
  int stride = gridDim.x * blockDim.x;
  for (; i < n; i += stride) { float2 v = x2[i]; xpk[i] = pack2(v.x, v.y); }
}

// W_ih (H,IN) -> [k2][n] dwords, k2 in [0,128), n in [0,512)
__global__ void k_pack_wih(const float* __restrict__ w, uint32_t* __restrict__ wp) {
  int i = blockIdx.x * 256 + threadIdx.x;   // 256 blocks -> 65536
  int k2 = i >> 9, n = i & 511;
  wp[i] = pack2(w[n * IN_ + 2 * k2], w[n * IN_ + 2 * k2 + 1]);
}

// W_ff (O,H) -> [k2][o] dwords, k2 in [0,256), o in [0,256)
__global__ void k_pack_wff(const float* __restrict__ w, uint32_t* __restrict__ wp) {
  int i = blockIdx.x * 256 + threadIdx.x;   // 256 blocks -> 65536
  int k2 = i >> 8, o = i & 255;
  wp[i] = pack2(w[o * H_ + 2 * k2], w[o * H_ + 2 * k2 + 1]);
}

// W_hh (H,H) -> uint4 quads: layout [g][o] with g in [0,64), o in [0,512)
// dword c of quad = (W[o][8g+2c], W[o][8g+2c+1]) as f16x2
__global__ void k_pack_whh(const float* __restrict__ w, uint32_t* __restrict__ wp) {
  int i = blockIdx.x * 256 + threadIdx.x;   // 512 blocks -> 131072 dwords
  int g = i >> 11, o = (i >> 2) & 511, c = i & 3;
  int k = 8 * g + 2 * c;
  wp[i] = pack2(w[o * H_ + k], w[o * H_ + k + 1]);
}

// ---------------- tiled fdot2 GEMM:  out[M][N] = A[M][K] * W[N][K]^T + bias ----
// apack: [M][K2] f16x2 dwords;  wpack: [k2][N] f16x2 dwords
// BM=128, BN=64, 256 threads, thread tile 4m x 8n, K staged 64 k2 at a time.

template <int NSTAGES>
__global__ void __launch_bounds__(256) k_gemm(
    const uint32_t* __restrict__ apack, const uint32_t* __restrict__ wpack,
    const float* __restrict__ bias0, const float* __restrict__ bias1,
    float* __restrict__ out, int Ncols)
{
  const int K2 = NSTAGES * 64;
  __shared__ uint32_t xs[128][65];   // [m][k2], padded: write 2-way (free), read broadcast
  __shared__ uint32_t ws[64][64];    // [k2][n]
  const int tid = threadIdx.x;
  const int mbase = blockIdx.x * 128;
  const int nbase = blockIdx.y * 64;
  const int tx = tid & 7, ty = tid >> 3;   // 8 n-groups x 32 m-groups
  const int m0 = ty * 4, n0 = tx * 8;

  float bs[8];
#pragma unroll
  for (int j = 0; j < 8; ++j) {
    int n = nbase + n0 + j;
    bs[j] = bias0[n] + (bias1 ? bias1[n] : 0.0f);
  }

  float acc[4][8];
#pragma unroll
  for (int i = 0; i < 4; ++i)
#pragma unroll
    for (int j = 0; j < 8; ++j) acc[i][j] = 0.0f;

  for (int s = 0; s < NSTAGES; ++s) {
    const int k2b = s * 64;
    __syncthreads();
#pragma unroll
    for (int c = 0; c < 32; ++c) {      // stage A tile: 8192 dwords
      int idx = c * 256 + tid;
      int m = idx >> 6, k2 = idx & 63;
      xs[m][k2] = apack[(size_t)(mbase + m) * K2 + k2b + k2];
    }
#pragma unroll
    for (int c = 0; c < 16; ++c) {      // stage W tile: 4096 dwords
      int idx = c * 256 + tid;
      int k2 = idx >> 6, n = idx & 63;
      ws[k2][n] = wpack[(size_t)(k2b + k2) * Ncols + nbase + n];
    }
    __syncthreads();
#pragma unroll 8
    for (int k2 = 0; k2 < 64; ++k2) {
      uint32_t xv[4];
#pragma unroll
      for (int i = 0; i < 4; ++i) xv[i] = xs[m0 + i][k2];
      uint4 wA = *(const uint4*)&ws[k2][n0];
      uint4 wB = *(const uint4*)&ws[k2][n0 + 4];
#pragma unroll
      for (int i = 0; i < 4; ++i) {
        acc[i][0] = fdot2(xv[i], wA.x, acc[i][0]);
        acc[i][1] = fdot2(xv[i], wA.y, acc[i][1]);
        acc[i][2] = fdot2(xv[i], wA.z, acc[i][2]);
        acc[i][3] = fdot2(xv[i], wA.w, acc[i][3]);
        acc[i][4] = fdot2(xv[i], wB.x, acc[i][4]);
        acc[i][5] = fdot2(xv[i], wB.y, acc[i][5]);
        acc[i][6] = fdot2(xv[i], wB.z, acc[i][6]);
        acc[i][7] = fdot2(xv[i], wB.w, acc[i][7]);
      }
    }
  }
#pragma unroll
  for (int i = 0; i < 4; ++i) {
    size_t row = (size_t)(mbase + m0 + i) * Ncols + nbase + n0;
    float4 r0 = make_float4(acc[i][0] + bs[0], acc[i][1] + bs[1],
                            acc[i][2] + bs[2], acc[i][3] + bs[3]);
    float4 r1 = make_float4(acc[i][4] + bs[4], acc[i][5] + bs[5],
                            acc[i][6] + bs[6], acc[i][7] + bs[7]);
    *(float4*)&out[row] = r0;
    *(float4*)&out[row + 4] = r1;
  }
}

// ---------------- persistent recurrence: 64 blocks (1/batch) x 512 threads ----
// thread t computes h_new[t] = tanh(xp[t] + dot(W_hh[t,:], h)) each step.
// W_hh row held as: 44 uint4 groups in regs, 7 in LDS, 13 streamed from L2.

#define RG 44
#define LG 7
#define SG 13

#define DOT4(W, HH)                               \
  { acc0 = fdot2((W).x, (HH).x, acc0);            \
    acc1 = fdot2((W).y, (HH).y, acc1);            \
    acc2 = fdot2((W).z, (HH).z, acc2);            \
    acc3 = fdot2((W).w, (HH).w, acc3); }

__global__ void __launch_bounds__(512, 2) k_rnn(
    const uint4* __restrict__ wq,     // [64][512] uint4 (k-groups x output-row)
    const float* __restrict__ xp,     // [B*S][H] f32
    const float* __restrict__ h0,     // [B][H] f32
    h16* __restrict__ hs)             // [B*S][H] f16
{
  __shared__ uint4 hq[H_ / 8];        // h as 512 f16 (64 uint4)
  __shared__ uint4 lw[LG][H_];        // LDS-resident W groups: 57344 B
  const int t = threadIdx.x;
  const int b = blockIdx.x;

  uint4 wr[RG];
#pragma unroll
  for (int g = 0; g < RG; ++g) wr[g] = wq[(size_t)g * H_ + t];
#pragma unroll
  for (int j = 0; j < LG; ++j) lw[j][t] = wq[(size_t)(RG + j) * H_ + t];
  ((unsigned short*)hq)[t] = __builtin_bit_cast(unsigned short, (h16)h0[(size_t)b * H_ + t]);

  const uint4* wstr = wq + (size_t)(RG + LG) * H_ + t;
  const float* xpb = xp + (size_t)b * S_ * H_ + t;
  h16* hsb = hs + (size_t)b * S_ * H_ + t;
  __syncthreads();

  for (int step = 0; step < S_; ++step) {
    float xv = xpb[(size_t)step * H_];
    float acc0 = 0.f, acc1 = 0.f, acc2 = 0.f, acc3 = 0.f;
    const uint4* h4 = (const uint4*)hq;
    uint4 sA[7], sB[6];
#pragma unroll
    for (int j = 0; j < 7; ++j) sA[j] = wstr[(size_t)j * H_];        // issue stream A
#pragma unroll
    for (int g = 0; g < 22; ++g) DOT4(wr[g], h4[g]);                 // covers latency
#pragma unroll
    for (int j = 0; j < 7; ++j) DOT4(sA[j], h4[RG + LG + j]);        // consume A
#pragma unroll
    for (int j = 0; j < 6; ++j) sB[j] = wstr[(size_t)(7 + j) * H_];  // issue stream B
#pragma unroll
    for (int g = 22; g < RG; ++g) DOT4(wr[g], h4[g]);
#pragma unroll
    for (int j = 0; j < LG; ++j) { uint4 w = lw[j][t]; DOT4(w, h4[RG + j]); }
#pragma unroll
    for (int j = 0; j < 6; ++j) DOT4(sB[j], h4[RG + LG + 7 + j]);    // consume B
    float hn = tanhf(((acc0 + acc1) + (acc2 + acc3)) + xv);
    __syncthreads();                  // all reads of h done
    ((unsigned short*)hq)[t] = __builtin_bit_cast(unsigned short, (h16)hn);
    hsb[(size_t)step * H_] = (h16)hn;
    __syncthreads();                  // h ready for next step
  }
}

// ---------------- host launch ----------------

extern "C" void kernel_launch(void* const* d_in, const int* in_sizes, int n_in,
                              void* d_out, int out_size, void* d_ws, size_t ws_size,
                              hipStream_t stream) {
  (void)in_sizes; (void)n_in; (void)out_size; (void)ws_size;
  const float* x   = (const float*)d_in[0];
  const float* h0  = (const float*)d_in[1];
  const float* Wih = (const float*)d_in[2];
  const float* Whh = (const float*)d_in[3];
  const float* bih = (const float*)d_in[4];
  const float* bhh = (const float*)d_in[5];
  const float* Wff = (const float*)d_in[6];
  const float* bff = (const float*)d_in[7];
  float* out = (float*)d_out;

  char* ws = (char*)d_ws;
  size_t off = 0;
  float* xp = (float*)(ws + off);        off += (size_t)B_ * S_ * H_ * 4;   // 67.1 MB
  uint32_t* xpk = (uint32_t*)(ws + off); off += (size_t)B_ * S_ * (IN_ / 2) * 4; // 16.8 MB
  h16* hs = (h16*)(ws + off);            off += (size_t)B_ * S_ * H_ * 2;   // 33.6 MB
  uint32_t* whq = (uint32_t*)(ws + off); off += (size_t)64 * H_ * 16;       // 0.5 MB
  uint32_t* wihp = (uint32_t*)(ws + off); off += (size_t)(IN_ / 2) * H_ * 4;
  uint32_t* wffp = (uint32_t*)(ws + off); off += (size_t)(H_ / 2) * O_ * 4;

  k_pack_x<<<2048, 256, 0, stream>>>((const float2*)x, xpk, B_ * S_ * (IN_ / 2));
  k_pack_wih<<<256, 256, 0, stream>>>(Wih, wihp);
  k_pack_whh<<<512, 256, 0, stream>>>(Whh, whq);
  k_pack_wff<<<256, 256, 0, stream>>>(Wff, wffp);

  // xp = x @ W_ih^T + b_ih + b_hh   (M=32768, N=512, K=256)
  k_gemm<2><<<dim3(256, 8), 256, 0, stream>>>(xpk, wihp, bih, bhh, xp, H_);
  // recurrence
  k_rnn<<<64, 512, 0, stream>>>((const uint4*)whq, xp, h0, hs);
  // out = hs @ W_ff^T + b_ff        (M=32768, N=256, K=512)
  k_gemm<4><<<dim3(256, 4), 256, 0, stream>>>((const uint32_t*)hs, wffp, bff, nullptr, out, O_);
}